// Round 8
// baseline (1668.161 us; speedup 1.0000x reference)
//
#include <hip/hip_runtime.h>
#include <hip/hip_bf16.h>
#include <math.h>

// LSTM language model. Round 8: fp16 hi/lo everywhere (21-bit effective).
// Recurrence: dataflow-synchronized persistent kernel (unchanged structure).
// Projection: 2-pass fp16 MFMA — A frags read DIRECT from h slots (no A-LDS),
// B = Wc single fp16 RNE.
// ws layout (~58.8 MB):
//   xWb    [128][16][4096] f32      33,554,432 B @ 0
//   ub_hi  [256ct][32kt][64][8] f16  8,388,608 B @ 33,554,432
//   ub_lo   (same)                   8,388,608 B @ 41,943,040
//   hslots [129][hi 16384 | lo 16384] ushort = 8,454,144 B @ 50,331,648
//          slot t: h_t fp16 hi/lo in A-fragment order; slot 0 zeroed (h0),
//          rest pre-poisoned 0xFFFF (fp16 NaN, unreachable by real data).

#define VOCAB 32000
#define EMBED 256
#define UNITS 1024
#define GATES 4096
#define BATCH 16
#define SEQ 128
#define NB 64   // persistent recurrence blocks

using s16x8 = __attribute__((ext_vector_type(8))) short;
using f16x8 = __attribute__((ext_vector_type(8))) _Float16;
using f32x4 = __attribute__((ext_vector_type(4))) float;

__device__ __forceinline__ unsigned short f16_bits(float x) {
    _Float16 h = (_Float16)x;                 // v_cvt_f16_f32, RNE
    return __builtin_bit_cast(unsigned short, h);
}
__device__ __forceinline__ float f16_f32(unsigned short b) {
    return (float)__builtin_bit_cast(_Float16, b);
}
__device__ __forceinline__ int swz_e(int r, int k) {
    return (r * 64 + k) ^ ((((r & 7) ^ ((r >> 2) & 7))) << 3);
}

// ---------- K0: U [1024][4096] -> fragment-ordered fp16 hi/lo ----------
// ub[ct][kt][lane][e]: col = ct*16 + (lane&15), k = kt*32 + (lane>>4)*8 + e
__global__ void __launch_bounds__(256) k_prep_ub(const float* __restrict__ U,
                                                 unsigned short* __restrict__ ub_hi,
                                                 unsigned short* __restrict__ ub_lo) {
    __shared__ float lds_u[1024 * 16];     // [k][16 cols], 64 KB
    const int ct = blockIdx.x;             // 0..255
    const int tid = threadIdx.x;
    for (int k = tid; k < 1024; k += 256) {
        const float4* src = (const float4*)(U + (size_t)k * GATES + ct * 16);
        float4* dst = (float4*)(&lds_u[k * 16]);
        dst[0] = src[0]; dst[1] = src[1]; dst[2] = src[2]; dst[3] = src[3];
    }
    __syncthreads();
    const int lane = tid & 63;
    const int coll = lane & 15;
    const int kg = lane >> 4;
    for (int kt = (tid >> 6); kt < 32; kt += 4) {
        const int ks = kt * 32 + kg * 8;
        unsigned short h8[8], l8[8];
#pragma unroll
        for (int e = 0; e < 8; ++e) {
            float v = lds_u[(ks + e) * 16 + coll];
            unsigned short hb = f16_bits(v);
            h8[e] = hb;
            l8[e] = f16_bits(v - f16_f32(hb));
        }
        size_t o = (((size_t)ct * 32 + kt) * 64 + lane) * 8;
        *(s16x8*)(ub_hi + o) = *(const s16x8*)h8;
        *(s16x8*)(ub_lo + o) = *(const s16x8*)l8;
    }
}

// ---------- K1: xWb[t][b][col] = emb[inputs[b][t]] @ W + bias ----------
__global__ void k_embed_xw(const int* __restrict__ inputs,
                           const float* __restrict__ emb,
                           const float* __restrict__ W,
                           const float* __restrict__ bias,
                           float* __restrict__ xWb) {
    const int t   = blockIdx.y;
    const int col = blockIdx.x * 256 + threadIdx.x;
    __shared__ float xs[BATCH][EMBED];
    __shared__ int   toks[BATCH];
    if (threadIdx.x < BATCH)
        toks[threadIdx.x] = inputs[threadIdx.x * SEQ + t];
    __syncthreads();
    for (int r = 0; r < BATCH; ++r)
        xs[r][threadIdx.x] = emb[(size_t)toks[r] * EMBED + threadIdx.x];
    __syncthreads();
    float acc[BATCH];
#pragma unroll
    for (int r = 0; r < BATCH; ++r) acc[r] = 0.f;
    for (int k = 0; k < EMBED; ++k) {
        float w = W[(size_t)k * GATES + col];
#pragma unroll
        for (int r = 0; r < BATCH; ++r) acc[r] += xs[r][k] * w;
    }
    const float bb = bias[col];
#pragma unroll
    for (int r = 0; r < BATCH; ++r)
        xWb[((size_t)t * BATCH + r) * GATES + col] = acc[r] + bb;
}

// ---------- K2: whole recurrence, persistent, dataflow-synchronized ----------
// 64 blocks x 256 thr (4 waves). Block owns cells j0..j0+15 across all 4
// gates; wave w covers k in [256w, 256w+256). U frags live in VGPRs.
// h slot layout (per step): elem(b, j) = (j>>5)*512 + (((j>>3)&3)*16 + b)*8
// + (j&7); hi plane at +0, lo plane at +16384 (ushort units).
// Sync: consumers poll their fragment words (relaxed agent sc1 u64 loads)
// until no 32-bit half equals the 0xFFFFFFFF poison; producers just store
// (relaxed sc1 u32). Write-once slots -> no barrier needed.
__global__ void __launch_bounds__(256, 1) k_lstm_all(
    const unsigned short* __restrict__ ub_hi,
    const unsigned short* __restrict__ ub_lo,
    const float* __restrict__ xWb,
    unsigned short* __restrict__ hsl) {
    __shared__ float zpart[4][4][256];     // [wave][gate][b*16+jj], 16 KB
    const int tid  = threadIdx.x;
    const int lane = tid & 63;
    const int w    = tid >> 6;             // k-slice 0..3
    const int bid  = blockIdx.x;
    const int j0   = bid * 16;

    const int b_own  = tid >> 4;           // batch row owned
    const int jj_own = tid & 15;           // local cell owned
    const int j_own  = j0 + jj_own;
    const int hb_e = ((j_own >> 5) * 512) + (((j_own >> 3) & 3) * 16 + b_own) * 8 + (j_own & 7);
    float c_own = 0.f;

    // ---- preload U fragments (once) ----
    f16x8 Uh[4][8], Ul[4][8];
#pragma unroll
    for (int g = 0; g < 4; ++g)
#pragma unroll
        for (int q = 0; q < 8; ++q) {
            size_t o = (((size_t)(g * 64 + bid) * 32) + (w * 8 + q)) * 512 + lane * 8;
            Uh[g][q] = *(const f16x8*)(ub_hi + o);
            Ul[g][q] = *(const f16x8*)(ub_lo + o);
        }

    for (int t = 0; t < SEQ; ++t) {
        // xW gather for owned cells (independent of h -> issues early)
        const float* xwp = xWb + ((size_t)t * BATCH + b_own) * GATES + j_own;
        float xw0 = xwp[0], xw1 = xwp[UNITS], xw2 = xwp[2 * UNITS], xw3 = xwp[3 * UNITS];

        // ---- poll + load this wave's h fragments for step t ----
        const unsigned long long* p64 =
            (const unsigned long long*)(hsl + (size_t)t * 32768);
        unsigned long long qh[16], ql[16];
        while (true) {
            unsigned bad = 0;
#pragma unroll
            for (int q = 0; q < 8; ++q) {
                const size_t u = (size_t)(w * 8 + q) * 128 + lane * 2;
                qh[2 * q]     = __hip_atomic_load(p64 + u,        __ATOMIC_RELAXED, __HIP_MEMORY_SCOPE_AGENT);
                qh[2 * q + 1] = __hip_atomic_load(p64 + u + 1,    __ATOMIC_RELAXED, __HIP_MEMORY_SCOPE_AGENT);
                ql[2 * q]     = __hip_atomic_load(p64 + 4096 + u, __ATOMIC_RELAXED, __HIP_MEMORY_SCOPE_AGENT);
                ql[2 * q + 1] = __hip_atomic_load(p64 + 4097 + u, __ATOMIC_RELAXED, __HIP_MEMORY_SCOPE_AGENT);
            }
#pragma unroll
            for (int i = 0; i < 16; ++i) {
                bad |= (unsigned)((unsigned)qh[i] == 0xFFFFFFFFu);
                bad |= (unsigned)((unsigned)(qh[i] >> 32) == 0xFFFFFFFFu);
                bad |= (unsigned)((unsigned)ql[i] == 0xFFFFFFFFu);
                bad |= (unsigned)((unsigned)(ql[i] >> 32) == 0xFFFFFFFFu);
            }
            if (__all((int)(bad == 0))) break;
            __builtin_amdgcn_s_sleep(2);
        }
        f16x8 Hh[8], Hl[8];
#pragma unroll
        for (int q = 0; q < 8; ++q) {
            union { unsigned long long q2[2]; f16x8 v; } uh, ul;
            uh.q2[0] = qh[2 * q]; uh.q2[1] = qh[2 * q + 1];
            ul.q2[0] = ql[2 * q]; ul.q2[1] = ql[2 * q + 1];
            Hh[q] = uh.v; Hl[q] = ul.v;
        }

        f32x4 a0[4], a1[4], a2[4];
#pragma unroll
        for (int g = 0; g < 4; ++g) {
            a0[g] = (f32x4){0.f, 0.f, 0.f, 0.f};
            a1[g] = (f32x4){0.f, 0.f, 0.f, 0.f};
            a2[g] = (f32x4){0.f, 0.f, 0.f, 0.f};
        }
#pragma unroll
        for (int q = 0; q < 8; ++q)
#pragma unroll
            for (int g = 0; g < 4; ++g) {
                a0[g] = __builtin_amdgcn_mfma_f32_16x16x32_f16(Hh[q], Uh[g][q], a0[g], 0, 0, 0);
                a1[g] = __builtin_amdgcn_mfma_f32_16x16x32_f16(Hh[q], Ul[g][q], a1[g], 0, 0, 0);
                a2[g] = __builtin_amdgcn_mfma_f32_16x16x32_f16(Hl[q], Uh[g][q], a2[g], 0, 0, 0);
            }

        __syncthreads();   // previous step's zpart reads complete
#pragma unroll
        for (int g = 0; g < 4; ++g)
#pragma unroll
            for (int r = 0; r < 4; ++r)
                zpart[w][g][((lane >> 4) * 4 + r) * 16 + (lane & 15)] =
                    a0[g][r] + a1[g][r] + a2[g][r];
        __syncthreads();

        // reduce across waves + activations for owned cell (b_own, j_own)
        const int zi_idx = b_own * 16 + jj_own;
        float zi = xw0, zf = xw1, zg = xw2, zo = xw3;
#pragma unroll
        for (int ww = 0; ww < 4; ++ww) {
            zi += zpart[ww][0][zi_idx];
            zf += zpart[ww][1][zi_idx];
            zg += zpart[ww][2][zi_idx];
            zo += zpart[ww][3][zi_idx];
        }
        float si = 1.f / (1.f + expf(-zi));
        float sf = 1.f / (1.f + expf(-zf));
        float so = 1.f / (1.f + expf(-zo));
        float c_new = sf * c_own + si * tanhf(zg);
        float h_new = so * tanhf(c_new);
        c_own = c_new;

        // pack lane-pairs (adjacent j) -> u32, relaxed sc1 store. Data IS
        // the completion signal (write-once slot, poison-checked by readers).
        int hhi = (int)f16_bits(h_new);
        int hlo = (int)f16_bits(h_new - f16_f32((unsigned short)hhi));
        int hhi_nb = __shfl_xor(hhi, 1);
        int hlo_nb = __shfl_xor(hlo, 1);
        unsigned short* nh = hsl + (size_t)(t + 1) * 32768;
        if ((tid & 1) == 0) {
            unsigned hp = (unsigned)(unsigned short)hhi | ((unsigned)(unsigned short)hhi_nb << 16);
            unsigned lp = (unsigned)(unsigned short)hlo | ((unsigned)(unsigned short)hlo_nb << 16);
            __hip_atomic_store((unsigned*)(nh + hb_e), hp,
                               __ATOMIC_RELAXED, __HIP_MEMORY_SCOPE_AGENT);
            __hip_atomic_store((unsigned*)(nh + 16384 + hb_e), lp,
                               __ATOMIC_RELAXED, __HIP_MEMORY_SCOPE_AGENT);
        }
        // no barrier: next step's poll provides all ordering.
    }
}

// ---------- K3: projection, 2-pass fp16 MFMA ----------
// out[m][n] = hs[m] @ Wc + bc, m = b*128 + t (b = mt). A = h hi/lo fp16 read
// as MFMA fragments DIRECT from hslots (no A-LDS): for lane l, frag row
// t̂ = wm + mi*16 + (l&15)  -> slot t̂+1;  j = kt*64 + ks*32 + kg*8  ->
// elem off = (2kt+ks)*512 + kg*128 + mt*8 (8 consecutive j = one 16B chunk).
// B = Wc cvt to fp16 (RNE), reg-transposed into swizzled LDS (16 KB).
__global__ void __launch_bounds__(256, 2) k_proj_mfma(
    const unsigned short* __restrict__ hsl,
    const float* __restrict__ Wc,
    const float* __restrict__ bc,
    float* __restrict__ out) {
    __shared__ unsigned short Bs[128 * 64];   // fp16 bits, swz_e layout

    const int tid = threadIdx.x;
    const int bid = blockIdx.x;
    const int swz = (bid & 7) * 500 + (bid >> 3);
    const int nt = swz / 16, mt = swz & 15;
    const int n0 = nt * 128;

    const int b_kb  = (tid >> 5) * 8;
    const int b_nb4 = (tid & 31) * 4;

    const int lane = tid & 63;
    const int w    = tid >> 6;
    const int wm   = (w >> 1) * 64;
    const int wn   = (w & 1) * 64;
    const int lr   = lane & 15;
    const int kg   = lane >> 4;

    f32x4 acc[4][4];
#pragma unroll
    for (int i = 0; i < 4; ++i)
#pragma unroll
        for (int j = 0; j < 4; ++j) acc[i][j] = (f32x4){0.f, 0.f, 0.f, 0.f};

    // per-lane A fragment bases (hi plane; lo at +16384)
    const unsigned short* abase[4];
#pragma unroll
    for (int mi = 0; mi < 4; ++mi)
        abase[mi] = hsl + (size_t)(wm + mi * 16 + lr + 1) * 32768 + (size_t)mt * 8;
    const int akg = kg * 128;

    // prologue: A frags for kt=0 (ks=0 -> A0, ks=1 -> A1), B raws for kt=0
    f16x8 A0h[4], A0l[4], A1h[4], A1l[4];
#pragma unroll
    for (int mi = 0; mi < 4; ++mi) {
        A0h[mi] = *(const f16x8*)(abase[mi] + akg);
        A0l[mi] = *(const f16x8*)(abase[mi] + akg + 16384);
        A1h[mi] = *(const f16x8*)(abase[mi] + 512 + akg);
        A1l[mi] = *(const f16x8*)(abase[mi] + 512 + akg + 16384);
    }
    float4 rawB[8];
#pragma unroll
    for (int i = 0; i < 8; ++i)
        rawB[i] = *(const float4*)(Wc + (size_t)(b_kb + i) * VOCAB + n0 + b_nb4);

    for (int kt = 0; kt < 16; ++kt) {
        __syncthreads();
        // ---- stage B: cvt f32->fp16 RNE, transpose in regs, b128 write ----
#pragma unroll
        for (int nn = 0; nn < 4; ++nn) {
            unsigned short h8[8];
#pragma unroll
            for (int i = 0; i < 8; ++i)
                h8[i] = f16_bits(((const float*)&rawB[i])[nn]);
            int e = swz_e(b_nb4 + nn, b_kb);
            *(s16x8*)(&Bs[e]) = *(const s16x8*)h8;
        }
        __syncthreads();
        if (kt < 15) {
            const int k0n = (kt + 1) * 64;
#pragma unroll
            for (int i = 0; i < 8; ++i)
                rawB[i] = *(const float4*)(Wc + (size_t)(k0n + b_kb + i) * VOCAB + n0 + b_nb4);
        }
        // ---- ks = 0: MFMA then refill A0 for kt+1 ----
        {
            f16x8 bh[4];
#pragma unroll
            for (int ni = 0; ni < 4; ++ni)
                bh[ni] = *(const f16x8*)(&Bs[swz_e(wn + ni * 16 + lr, kg * 8)]);
#pragma unroll
            for (int mi = 0; mi < 4; ++mi)
#pragma unroll
                for (int ni = 0; ni < 4; ++ni) {
                    acc[mi][ni] = __builtin_amdgcn_mfma_f32_16x16x32_f16(A0h[mi], bh[ni], acc[mi][ni], 0, 0, 0);
                    acc[mi][ni] = __builtin_amdgcn_mfma_f32_16x16x32_f16(A0l[mi], bh[ni], acc[mi][ni], 0, 0, 0);
                }
            if (kt < 15) {
                const int base = (kt + 1) * 1024;   // (2*(kt+1)+0)*512
#pragma unroll
                for (int mi = 0; mi < 4; ++mi) {
                    A0h[mi] = *(const f16x8*)(abase[mi] + base + akg);
                    A0l[mi] = *(const f16x8*)(abase[mi] + base + akg + 16384);
                }
            }
        }
        // ---- ks = 1: MFMA then refill A1 for kt+1 ----
        {
            f16x8 bh[4];
#pragma unroll
            for (int ni = 0; ni < 4; ++ni)
                bh[ni] = *(const f16x8*)(&Bs[swz_e(wn + ni * 16 + lr, 32 + kg * 8)]);
#pragma unroll
            for (int mi = 0; mi < 4; ++mi)
#pragma unroll
                for (int ni = 0; ni < 4; ++ni) {
                    acc[mi][ni] = __builtin_amdgcn_mfma_f32_16x16x32_f16(A1h[mi], bh[ni], acc[mi][ni], 0, 0, 0);
                    acc[mi][ni] = __builtin_amdgcn_mfma_f32_16x16x32_f16(A1l[mi], bh[ni], acc[mi][ni], 0, 0, 0);
                }
            if (kt < 15) {
                const int base = (kt + 1) * 1024 + 512;   // (2*(kt+1)+1)*512
#pragma unroll
                for (int mi = 0; mi < 4; ++mi) {
                    A1h[mi] = *(const f16x8*)(abase[mi] + base + akg);
                    A1l[mi] = *(const f16x8*)(abase[mi] + base + akg + 16384);
                }
            }
        }
    }

    // ---- epilogue: C/D layout col = lane&15, row = (lane>>4)*4 + reg ----
    float bcv[4];
#pragma unroll
    for (int ni = 0; ni < 4; ++ni) bcv[ni] = bc[n0 + wn + ni * 16 + lr];
#pragma unroll
    for (int mi = 0; mi < 4; ++mi) {
#pragma unroll
        for (int ni = 0; ni < 4; ++ni) {
#pragma unroll
            for (int r = 0; r < 4; ++r) {
                int grow = mt * 128 + wm + mi * 16 + kg * 4 + r;
                int gcol = n0 + wn + ni * 16 + lr;
                out[(size_t)grow * VOCAB + gcol] = acc[mi][ni][r] + bcv[ni];
            }
        }
    }
}

extern "C" void kernel_launch(void* const* d_in, const int* in_sizes, int n_in,
                              void* d_out, int out_size, void* d_ws, size_t ws_size,
                              hipStream_t stream) {
    const int*   inputs = (const int*)d_in[0];   // int32 (JAX x64 disabled)
    const float* emb  = (const float*)d_in[1];
    const float* W    = (const float*)d_in[2];
    const float* U    = (const float*)d_in[3];
    const float* bias = (const float*)d_in[4];
    const float* Wc   = (const float*)d_in[5];
    const float* bc   = (const float*)d_in[6];
    float* out = (float*)d_out;

    char* ws = (char*)d_ws;
    float*          xWb   = (float*)(ws + 0);
    unsigned short* ub_hi = (unsigned short*)(ws + 33554432);
    unsigned short* ub_lo = (unsigned short*)(ws + 41943040);
    unsigned short* hsl   = (unsigned short*)(ws + 50331648);

    // slot 0 = h0 = 0 (valid); slots 1..128 poisoned 0xFFFF — every call
    hipMemsetAsync(hsl, 0, 65536, stream);
    hipMemsetAsync((char*)hsl + 65536, 0xFF, 8454144 - 65536, stream);

    k_prep_ub<<<256, 256, 0, stream>>>(U, ub_hi, ub_lo);
    k_embed_xw<<<dim3(16, 128), 256, 0, stream>>>(inputs, emb, W, bias, xWb);
    k_lstm_all<<<NB, 256, 0, stream>>>(ub_hi, ub_lo, xWb, hsl);
    k_proj_mfma<<<4000, 256, 0, stream>>>(hsl, Wc, bc, out);
}

// Round 9
// 961.053 us; speedup vs baseline: 1.7358x; 1.7358x over previous
//
#include <hip/hip_runtime.h>
#include <hip/hip_bf16.h>
#include <math.h>

// LSTM language model. Round 9: projection m-tile remapped to {16 batches} x
// {8 t} so A fragments (frag row = batch) read as CONTIGUOUS 1KB/wave blocks
// straight from h slots — fixes round 8's 32KB-per-lane scatter. Recurrence
// unchanged (fp16 hi/lo, dataflow-synchronized).
// ws layout (~58.8 MB):
//   xWb    [128][16][4096] f32      33,554,432 B @ 0
//   ub_hi  [256ct][32kt][64][8] f16  8,388,608 B @ 33,554,432
//   ub_lo   (same)                   8,388,608 B @ 41,943,040
//   hslots [129][hi 16384 | lo 16384] ushort = 8,454,144 B @ 50,331,648
//          slot t: h_t fp16 hi/lo, elem(b,j) = (j>>5)*512 + (((j>>3)&3)*16+b)*8
//          + (j&7); slot 0 zeroed (h0), rest poisoned 0xFFFF (fp16 NaN).

#define VOCAB 32000
#define EMBED 256
#define UNITS 1024
#define GATES 4096
#define BATCH 16
#define SEQ 128
#define NB 64   // persistent recurrence blocks

using s16x8 = __attribute__((ext_vector_type(8))) short;
using f16x8 = __attribute__((ext_vector_type(8))) _Float16;
using f32x4 = __attribute__((ext_vector_type(4))) float;

__device__ __forceinline__ unsigned short f16_bits(float x) {
    _Float16 h = (_Float16)x;                 // v_cvt_f16_f32, RNE
    return __builtin_bit_cast(unsigned short, h);
}
__device__ __forceinline__ float f16_f32(unsigned short b) {
    return (float)__builtin_bit_cast(_Float16, b);
}
__device__ __forceinline__ int swz_e(int r, int k) {
    return (r * 64 + k) ^ ((((r & 7) ^ ((r >> 2) & 7))) << 3);
}

// ---------- K0: U [1024][4096] -> fragment-ordered fp16 hi/lo ----------
// ub[ct][kt][lane][e]: col = ct*16 + (lane&15), k = kt*32 + (lane>>4)*8 + e
__global__ void __launch_bounds__(256) k_prep_ub(const float* __restrict__ U,
                                                 unsigned short* __restrict__ ub_hi,
                                                 unsigned short* __restrict__ ub_lo) {
    __shared__ float lds_u[1024 * 16];     // [k][16 cols], 64 KB
    const int ct = blockIdx.x;             // 0..255
    const int tid = threadIdx.x;
    for (int k = tid; k < 1024; k += 256) {
        const float4* src = (const float4*)(U + (size_t)k * GATES + ct * 16);
        float4* dst = (float4*)(&lds_u[k * 16]);
        dst[0] = src[0]; dst[1] = src[1]; dst[2] = src[2]; dst[3] = src[3];
    }
    __syncthreads();
    const int lane = tid & 63;
    const int coll = lane & 15;
    const int kg = lane >> 4;
    for (int kt = (tid >> 6); kt < 32; kt += 4) {
        const int ks = kt * 32 + kg * 8;
        unsigned short h8[8], l8[8];
#pragma unroll
        for (int e = 0; e < 8; ++e) {
            float v = lds_u[(ks + e) * 16 + coll];
            unsigned short hb = f16_bits(v);
            h8[e] = hb;
            l8[e] = f16_bits(v - f16_f32(hb));
        }
        size_t o = (((size_t)ct * 32 + kt) * 64 + lane) * 8;
        *(s16x8*)(ub_hi + o) = *(const s16x8*)h8;
        *(s16x8*)(ub_lo + o) = *(const s16x8*)l8;
    }
}

// ---------- K1: xWb[t][b][col] = emb[inputs[b][t]] @ W + bias ----------
__global__ void k_embed_xw(const int* __restrict__ inputs,
                           const float* __restrict__ emb,
                           const float* __restrict__ W,
                           const float* __restrict__ bias,
                           float* __restrict__ xWb) {
    const int t   = blockIdx.y;
    const int col = blockIdx.x * 256 + threadIdx.x;
    __shared__ float xs[BATCH][EMBED];
    __shared__ int   toks[BATCH];
    if (threadIdx.x < BATCH)
        toks[threadIdx.x] = inputs[threadIdx.x * SEQ + t];
    __syncthreads();
    for (int r = 0; r < BATCH; ++r)
        xs[r][threadIdx.x] = emb[(size_t)toks[r] * EMBED + threadIdx.x];
    __syncthreads();
    float acc[BATCH];
#pragma unroll
    for (int r = 0; r < BATCH; ++r) acc[r] = 0.f;
    for (int k = 0; k < EMBED; ++k) {
        float w = W[(size_t)k * GATES + col];
#pragma unroll
        for (int r = 0; r < BATCH; ++r) acc[r] += xs[r][k] * w;
    }
    const float bb = bias[col];
#pragma unroll
    for (int r = 0; r < BATCH; ++r)
        xWb[((size_t)t * BATCH + r) * GATES + col] = acc[r] + bb;
}

// ---------- K2: whole recurrence, persistent, dataflow-synchronized ----------
// 64 blocks x 256 thr (4 waves). Block owns cells j0..j0+15 across all 4
// gates; wave w covers k in [256w, 256w+256). U frags live in VGPRs.
// Sync: consumers poll their fragment words (relaxed agent sc1 u64 loads)
// until no 32-bit half equals the 0xFFFFFFFF poison; producers just store
// (relaxed sc1 u32). Write-once slots -> no barrier needed.
__global__ void __launch_bounds__(256, 1) k_lstm_all(
    const unsigned short* __restrict__ ub_hi,
    const unsigned short* __restrict__ ub_lo,
    const float* __restrict__ xWb,
    unsigned short* __restrict__ hsl) {
    __shared__ float zpart[4][4][256];     // [wave][gate][b*16+jj], 16 KB
    const int tid  = threadIdx.x;
    const int lane = tid & 63;
    const int w    = tid >> 6;             // k-slice 0..3
    const int bid  = blockIdx.x;
    const int j0   = bid * 16;

    const int b_own  = tid >> 4;           // batch row owned
    const int jj_own = tid & 15;           // local cell owned
    const int j_own  = j0 + jj_own;
    const int hb_e = ((j_own >> 5) * 512) + (((j_own >> 3) & 3) * 16 + b_own) * 8 + (j_own & 7);
    float c_own = 0.f;

    // ---- preload U fragments (once) ----
    f16x8 Uh[4][8], Ul[4][8];
#pragma unroll
    for (int g = 0; g < 4; ++g)
#pragma unroll
        for (int q = 0; q < 8; ++q) {
            size_t o = (((size_t)(g * 64 + bid) * 32) + (w * 8 + q)) * 512 + lane * 8;
            Uh[g][q] = *(const f16x8*)(ub_hi + o);
            Ul[g][q] = *(const f16x8*)(ub_lo + o);
        }

    for (int t = 0; t < SEQ; ++t) {
        // xW gather for owned cells (independent of h -> issues early)
        const float* xwp = xWb + ((size_t)t * BATCH + b_own) * GATES + j_own;
        float xw0 = xwp[0], xw1 = xwp[UNITS], xw2 = xwp[2 * UNITS], xw3 = xwp[3 * UNITS];

        // ---- poll + load this wave's h fragments for step t ----
        const unsigned long long* p64 =
            (const unsigned long long*)(hsl + (size_t)t * 32768);
        unsigned long long qh[16], ql[16];
        while (true) {
            unsigned bad = 0;
#pragma unroll
            for (int q = 0; q < 8; ++q) {
                const size_t u = (size_t)(w * 8 + q) * 128 + lane * 2;
                qh[2 * q]     = __hip_atomic_load(p64 + u,        __ATOMIC_RELAXED, __HIP_MEMORY_SCOPE_AGENT);
                qh[2 * q + 1] = __hip_atomic_load(p64 + u + 1,    __ATOMIC_RELAXED, __HIP_MEMORY_SCOPE_AGENT);
                ql[2 * q]     = __hip_atomic_load(p64 + 4096 + u, __ATOMIC_RELAXED, __HIP_MEMORY_SCOPE_AGENT);
                ql[2 * q + 1] = __hip_atomic_load(p64 + 4097 + u, __ATOMIC_RELAXED, __HIP_MEMORY_SCOPE_AGENT);
            }
#pragma unroll
            for (int i = 0; i < 16; ++i) {
                bad |= (unsigned)((unsigned)qh[i] == 0xFFFFFFFFu);
                bad |= (unsigned)((unsigned)(qh[i] >> 32) == 0xFFFFFFFFu);
                bad |= (unsigned)((unsigned)ql[i] == 0xFFFFFFFFu);
                bad |= (unsigned)((unsigned)(ql[i] >> 32) == 0xFFFFFFFFu);
            }
            if (__all((int)(bad == 0))) break;
            __builtin_amdgcn_s_sleep(2);
        }
        f16x8 Hh[8], Hl[8];
#pragma unroll
        for (int q = 0; q < 8; ++q) {
            union { unsigned long long q2[2]; f16x8 v; } uh, ul;
            uh.q2[0] = qh[2 * q]; uh.q2[1] = qh[2 * q + 1];
            ul.q2[0] = ql[2 * q]; ul.q2[1] = ql[2 * q + 1];
            Hh[q] = uh.v; Hl[q] = ul.v;
        }

        f32x4 a0[4], a1[4], a2[4];
#pragma unroll
        for (int g = 0; g < 4; ++g) {
            a0[g] = (f32x4){0.f, 0.f, 0.f, 0.f};
            a1[g] = (f32x4){0.f, 0.f, 0.f, 0.f};
            a2[g] = (f32x4){0.f, 0.f, 0.f, 0.f};
        }
#pragma unroll
        for (int q = 0; q < 8; ++q)
#pragma unroll
            for (int g = 0; g < 4; ++g) {
                a0[g] = __builtin_amdgcn_mfma_f32_16x16x32_f16(Hh[q], Uh[g][q], a0[g], 0, 0, 0);
                a1[g] = __builtin_amdgcn_mfma_f32_16x16x32_f16(Hh[q], Ul[g][q], a1[g], 0, 0, 0);
                a2[g] = __builtin_amdgcn_mfma_f32_16x16x32_f16(Hl[q], Uh[g][q], a2[g], 0, 0, 0);
            }

        __syncthreads();   // previous step's zpart reads complete
#pragma unroll
        for (int g = 0; g < 4; ++g)
#pragma unroll
            for (int r = 0; r < 4; ++r)
                zpart[w][g][((lane >> 4) * 4 + r) * 16 + (lane & 15)] =
                    a0[g][r] + a1[g][r] + a2[g][r];
        __syncthreads();

        // reduce across waves + activations for owned cell (b_own, j_own)
        const int zi_idx = b_own * 16 + jj_own;
        float zi = xw0, zf = xw1, zg = xw2, zo = xw3;
#pragma unroll
        for (int ww = 0; ww < 4; ++ww) {
            zi += zpart[ww][0][zi_idx];
            zf += zpart[ww][1][zi_idx];
            zg += zpart[ww][2][zi_idx];
            zo += zpart[ww][3][zi_idx];
        }
        float si = 1.f / (1.f + expf(-zi));
        float sf = 1.f / (1.f + expf(-zf));
        float so = 1.f / (1.f + expf(-zo));
        float c_new = sf * c_own + si * tanhf(zg);
        float h_new = so * tanhf(c_new);
        c_own = c_new;

        // pack lane-pairs (adjacent j) -> u32, relaxed sc1 store. Data IS
        // the completion signal (write-once slot, poison-checked by readers).
        int hhi = (int)f16_bits(h_new);
        int hlo = (int)f16_bits(h_new - f16_f32((unsigned short)hhi));
        int hhi_nb = __shfl_xor(hhi, 1);
        int hlo_nb = __shfl_xor(hlo, 1);
        unsigned short* nh = hsl + (size_t)(t + 1) * 32768;
        if ((tid & 1) == 0) {
            unsigned hp = (unsigned)(unsigned short)hhi | ((unsigned)(unsigned short)hhi_nb << 16);
            unsigned lp = (unsigned)(unsigned short)hlo | ((unsigned)(unsigned short)hlo_nb << 16);
            __hip_atomic_store((unsigned*)(nh + hb_e), hp,
                               __ATOMIC_RELAXED, __HIP_MEMORY_SCOPE_AGENT);
            __hip_atomic_store((unsigned*)(nh + 16384 + hb_e), lp,
                               __ATOMIC_RELAXED, __HIP_MEMORY_SCOPE_AGENT);
        }
        // no barrier: next step's poll provides all ordering.
    }
}

// ---------- K3: projection, 2-pass fp16 MFMA, batch-major m-tiles ----------
// out[m][n], m = b*128 + t. m-tile mt2 covers {all 16 b} x {t in mt2*8..+8}.
// Frag row = batch b -> lane l's A elements are at slot_base + (2kt+ks)*512
// + l*8: one contiguous 1KB block per wave per (kt,ks,plane). No A-LDS, no
// A-cvt, fully coalesced. B = Wc fp16 RNE via swizzled LDS (16 KB).
__global__ void __launch_bounds__(256, 2) k_proj_mfma(
    const unsigned short* __restrict__ hsl,
    const float* __restrict__ Wc,
    const float* __restrict__ bc,
    float* __restrict__ out) {
    __shared__ unsigned short Bs[128 * 64];   // fp16 bits, swz_e layout

    const int tid = threadIdx.x;
    const int bid = blockIdx.x;
    const int swz = (bid & 7) * 500 + (bid >> 3);
    const int nt = swz / 16, mt2 = swz & 15;   // mt2 = t-block (8 t's)
    const int n0 = nt * 128;

    const int b_kb  = (tid >> 5) * 8;
    const int b_nb4 = (tid & 31) * 4;

    const int lane = tid & 63;
    const int w    = tid >> 6;
    const int wmt  = (w >> 1) * 4;    // wave t-offset within the 8-t tile
    const int wn   = (w & 1) * 64;
    const int lr   = lane & 15;
    const int kg   = lane >> 4;

    f32x4 acc[4][4];                  // [mi -> t][ni]
#pragma unroll
    for (int i = 0; i < 4; ++i)
#pragma unroll
        for (int j = 0; j < 4; ++j) acc[i][j] = (f32x4){0.f, 0.f, 0.f, 0.f};

    // per-frag A base: slot = mt2*8 + wmt + mi + 1; lane chunk = lane*8
    const unsigned short* aslot[4];
#pragma unroll
    for (int mi = 0; mi < 4; ++mi)
        aslot[mi] = hsl + (size_t)(mt2 * 8 + wmt + mi + 1) * 32768 + lane * 8;

    // prologue: A frags for kt=0 (ks=0 -> A0, ks=1 -> A1), B raws for kt=0
    f16x8 A0h[4], A0l[4], A1h[4], A1l[4];
#pragma unroll
    for (int mi = 0; mi < 4; ++mi) {
        A0h[mi] = *(const f16x8*)(aslot[mi]);
        A0l[mi] = *(const f16x8*)(aslot[mi] + 16384);
        A1h[mi] = *(const f16x8*)(aslot[mi] + 512);
        A1l[mi] = *(const f16x8*)(aslot[mi] + 512 + 16384);
    }
    float4 rawB[8];
#pragma unroll
    for (int i = 0; i < 8; ++i)
        rawB[i] = *(const float4*)(Wc + (size_t)(b_kb + i) * VOCAB + n0 + b_nb4);

    for (int kt = 0; kt < 16; ++kt) {
        __syncthreads();
        // ---- stage B: cvt f32->fp16 RNE, transpose in regs, b128 write ----
#pragma unroll
        for (int nn = 0; nn < 4; ++nn) {
            unsigned short h8[8];
#pragma unroll
            for (int i = 0; i < 8; ++i)
                h8[i] = f16_bits(((const float*)&rawB[i])[nn]);
            int e = swz_e(b_nb4 + nn, b_kb);
            *(s16x8*)(&Bs[e]) = *(const s16x8*)h8;
        }
        __syncthreads();
        if (kt < 15) {
            const int k0n = (kt + 1) * 64;
#pragma unroll
            for (int i = 0; i < 8; ++i)
                rawB[i] = *(const float4*)(Wc + (size_t)(k0n + b_kb + i) * VOCAB + n0 + b_nb4);
        }
        // ---- ks = 0: MFMA then refill A0 for kt+1 ----
        {
            f16x8 bh[4];
#pragma unroll
            for (int ni = 0; ni < 4; ++ni)
                bh[ni] = *(const f16x8*)(&Bs[swz_e(wn + ni * 16 + lr, kg * 8)]);
#pragma unroll
            for (int mi = 0; mi < 4; ++mi)
#pragma unroll
                for (int ni = 0; ni < 4; ++ni) {
                    acc[mi][ni] = __builtin_amdgcn_mfma_f32_16x16x32_f16(A0h[mi], bh[ni], acc[mi][ni], 0, 0, 0);
                    acc[mi][ni] = __builtin_amdgcn_mfma_f32_16x16x32_f16(A0l[mi], bh[ni], acc[mi][ni], 0, 0, 0);
                }
            if (kt < 15) {
                const int base = (kt + 1) * 1024;
#pragma unroll
                for (int mi = 0; mi < 4; ++mi) {
                    A0h[mi] = *(const f16x8*)(aslot[mi] + base);
                    A0l[mi] = *(const f16x8*)(aslot[mi] + base + 16384);
                }
            }
        }
        // ---- ks = 1: MFMA then refill A1 for kt+1 ----
        {
            f16x8 bh[4];
#pragma unroll
            for (int ni = 0; ni < 4; ++ni)
                bh[ni] = *(const f16x8*)(&Bs[swz_e(wn + ni * 16 + lr, 32 + kg * 8)]);
#pragma unroll
            for (int mi = 0; mi < 4; ++mi)
#pragma unroll
                for (int ni = 0; ni < 4; ++ni) {
                    acc[mi][ni] = __builtin_amdgcn_mfma_f32_16x16x32_f16(A1h[mi], bh[ni], acc[mi][ni], 0, 0, 0);
                    acc[mi][ni] = __builtin_amdgcn_mfma_f32_16x16x32_f16(A1l[mi], bh[ni], acc[mi][ni], 0, 0, 0);
                }
            if (kt < 15) {
                const int base = (kt + 1) * 1024 + 512;
#pragma unroll
                for (int mi = 0; mi < 4; ++mi) {
                    A1h[mi] = *(const f16x8*)(aslot[mi] + base);
                    A1l[mi] = *(const f16x8*)(aslot[mi] + base + 16384);
                }
            }
        }
    }

    // ---- epilogue: C/D col = lane&15 (n), row = kg*4 + r (= batch b) ----
    float bcv[4];
#pragma unroll
    for (int ni = 0; ni < 4; ++ni) bcv[ni] = bc[n0 + wn + ni * 16 + lr];
#pragma unroll
    for (int mi = 0; mi < 4; ++mi) {
        const int trow = mt2 * 8 + wmt + mi;
#pragma unroll
        for (int ni = 0; ni < 4; ++ni) {
#pragma unroll
            for (int r = 0; r < 4; ++r) {
                int grow = (kg * 4 + r) * 128 + trow;     // m = b*128 + t
                int gcol = n0 + wn + ni * 16 + lr;
                out[(size_t)grow * VOCAB + gcol] = acc[mi][ni][r] + bcv[ni];
            }
        }
    }
}

extern "C" void kernel_launch(void* const* d_in, const int* in_sizes, int n_in,
                              void* d_out, int out_size, void* d_ws, size_t ws_size,
                              hipStream_t stream) {
    const int*   inputs = (const int*)d_in[0];   // int32 (JAX x64 disabled)
    const float* emb  = (const float*)d_in[1];
    const float* W    = (const float*)d_in[2];
    const float* U    = (const float*)d_in[3];
    const float* bias = (const float*)d_in[4];
    const float* Wc   = (const float*)d_in[5];
    const float* bc   = (const float*)d_in[6];
    float* out = (float*)d_out;

    char* ws = (char*)d_ws;
    float*          xWb   = (float*)(ws + 0);
    unsigned short* ub_hi = (unsigned short*)(ws + 33554432);
    unsigned short* ub_lo = (unsigned short*)(ws + 41943040);
    unsigned short* hsl   = (unsigned short*)(ws + 50331648);

    // slot 0 = h0 = 0 (valid); slots 1..128 poisoned 0xFFFF — every call
    hipMemsetAsync(hsl, 0, 65536, stream);
    hipMemsetAsync((char*)hsl + 65536, 0xFF, 8454144 - 65536, stream);

    k_prep_ub<<<256, 256, 0, stream>>>(U, ub_hi, ub_lo);
    k_embed_xw<<<dim3(16, 128), 256, 0, stream>>>(inputs, emb, W, bias, xWb);
    k_lstm_all<<<NB, 256, 0, stream>>>(ub_hi, ub_lo, xWb, hsl);
    k_proj_mfma<<<4000, 256, 0, stream>>>(hsl, Wc, bc, out);
}